// Round 2
// baseline (2559.624 us; speedup 1.0000x reference)
//
#include <hip/hip_runtime.h>
#include <math.h>

#define BB 4
#define SS 1024
#define DD 768
#define HH 12
#define DHH 64

// ======================================================================
// GEMM: C = A[M=4096,768] @ W[768,768] + bias ; output layout per mode
//   mode 0: out[b][h][s][d]   [B,H,S,DH]   (Q, V)
//   mode 1: out[b][h][d][s]   [B,H,DH,S]   (K transposed for coalesced QK^T)
//   mode 2: out[m][n]         plain row-major
// 64x64 tile, BK=16, 256 threads, 4x4 per thread.
// ======================================================================
__global__ __launch_bounds__(256)
void gemm768_kernel(const float* __restrict__ A, const float* __restrict__ W,
                    const float* __restrict__ bias, float* __restrict__ out,
                    int mode)
{
    __shared__ float As[16][68];   // [k][m], padded: row 272B (16B aligned, 2-way max)
    __shared__ float Bs[16][64];   // [k][n]
    const int tid = threadIdx.x;
    const int tx = tid & 15, ty = tid >> 4;
    const int m0 = blockIdx.x * 64;
    const int n0 = blockIdx.y * 64;
    const int arow = tid >> 2, akq = tid & 3;

    float c[4][4] = {};

    for (int k0 = 0; k0 < 768; k0 += 16) {
        float4 av = *(const float4*)&A[(m0 + arow) * 768 + k0 + akq * 4];
        float4 bv = *(const float4*)&W[(k0 + ty) * 768 + n0 + tx * 4];
        As[akq * 4 + 0][arow] = av.x;
        As[akq * 4 + 1][arow] = av.y;
        As[akq * 4 + 2][arow] = av.z;
        As[akq * 4 + 3][arow] = av.w;
        *(float4*)&Bs[ty][tx * 4] = bv;
        __syncthreads();
        #pragma unroll
        for (int kk = 0; kk < 16; ++kk) {
            float4 a = *(const float4*)&As[kk][ty * 4];
            float4 b = *(const float4*)&Bs[kk][tx * 4];
            float am[4] = {a.x, a.y, a.z, a.w};
            float bn[4] = {b.x, b.y, b.z, b.w};
            #pragma unroll
            for (int i = 0; i < 4; ++i)
                #pragma unroll
                for (int j = 0; j < 4; ++j)
                    c[i][j] = fmaf(am[i], bn[j], c[i][j]);
        }
        __syncthreads();
    }

    #pragma unroll
    for (int i = 0; i < 4; ++i) {
        const int m = m0 + ty * 4 + i;
        const int b = m >> 10, s = m & 1023;
        #pragma unroll
        for (int j = 0; j < 4; ++j) {
            const int n = n0 + tx * 4 + j;
            const float val = c[i][j] + bias[n];
            if (mode == 0) {
                const int h = n >> 6, d = n & 63;
                out[(((b * HH + h) * SS) + s) * DHH + d] = val;
            } else if (mode == 1) {
                const int h = n >> 6, d = n & 63;
                out[(((b * HH + h) * DHH) + d) * SS + s] = val;
            } else {
                out[m * DD + n] = val;
            }
        }
    }
}

// ======================================================================
// Fused attention: per block = (b, 8 consecutive q rows), all 12 heads.
//   Pass 1: Z1[h][qb] = sum_k exp(q.k/8 + mask)          (no max needed; |s|<~3)
//   Pass 2 (per 64-k tile): recompute e1, p1=e1/Z1;
//     mix = conv_w@prev + conv_b; e2 = exp(.5*mix + .5*p1);
//     ctx += e2*V ; Z2 += e2 ; final ctx /= Z2.
// ======================================================================
__global__ __launch_bounds__(256)
void attn_kernel(const float* __restrict__ Q, const float* __restrict__ Kt,
                 const float* __restrict__ V, const float* __restrict__ prev,
                 const float* __restrict__ mask, const float* __restrict__ cw,
                 const float* __restrict__ cb, float* __restrict__ ctx)
{
    __shared__ float Qs[12][8][64];     // 24 KiB
    __shared__ float e2s[12][8][64];    // 24 KiB (per-k-tile e2 values)
    __shared__ float prevt[12][8][64];  // 24 KiB (per-k-tile prev rows)
    __shared__ float Z1s[12][8];
    __shared__ float Z2s[12][8];
    __shared__ float cws[12][12];
    __shared__ float cbs[12];

    const int tid  = threadIdx.x;
    const int lane = tid & 63;
    const int wave = tid >> 6;
    const int blk  = blockIdx.x;
    const int b    = blk >> 7;            // 128 q-tiles per batch
    const int q0   = (blk & 127) * 8;

    // ---- load Q tile (12 heads x 8 rows x 64) ----
    for (int idx = tid; idx < 1536; idx += 256) {
        const int d4 = idx & 15, qb = (idx >> 4) & 7, h = idx >> 7;
        float4 v = *(const float4*)&Q[(((b * HH + h) * SS) + q0 + qb) * DHH + d4 * 4];
        *(float4*)&Qs[h][qb][d4 * 4] = v;
    }
    if (tid < 144) cws[tid / 12][tid % 12] = cw[tid];
    if (tid < 12)  cbs[tid] = cb[tid];
    __syncthreads();

    // ---- pass 1: Z1 ----
    float invZ1[3][8];
    #pragma unroll
    for (int hi = 0; hi < 3; ++hi) {
        const int h = hi * 4 + wave;
        float zacc[8] = {};
        const float* kp = Kt + (size_t)(b * HH + h) * DHH * SS + lane;
        for (int kt = 0; kt < 16; ++kt) {
            float s[8] = {};
            const float* kpp = kp + kt * 64;
            #pragma unroll 4
            for (int d = 0; d < 64; d += 4) {
                const float kv0 = kpp[(d + 0) << 10];
                const float kv1 = kpp[(d + 1) << 10];
                const float kv2 = kpp[(d + 2) << 10];
                const float kv3 = kpp[(d + 3) << 10];
                #pragma unroll
                for (int qb = 0; qb < 8; ++qb) {
                    float4 qv = *(const float4*)&Qs[h][qb][d];
                    s[qb] = fmaf(qv.x, kv0, s[qb]);
                    s[qb] = fmaf(qv.y, kv1, s[qb]);
                    s[qb] = fmaf(qv.z, kv2, s[qb]);
                    s[qb] = fmaf(qv.w, kv3, s[qb]);
                }
            }
            const float mk = mask[b * SS + kt * 64 + lane];
            #pragma unroll
            for (int qb = 0; qb < 8; ++qb)
                zacc[qb] += __expf(s[qb] * 0.125f + mk);
        }
        #pragma unroll
        for (int qb = 0; qb < 8; ++qb) {
            float z = zacc[qb];
            for (int off = 32; off; off >>= 1) z += __shfl_xor(z, off);
            if (lane == 0) Z1s[h][qb] = z;
        }
    }
    __syncthreads();
    #pragma unroll
    for (int hi = 0; hi < 3; ++hi) {
        const int h = hi * 4 + wave;
        #pragma unroll
        for (int qb = 0; qb < 8; ++qb) invZ1[hi][qb] = 1.0f / Z1s[h][qb];
    }

    // ---- pass 2 ----
    float acc[3][8] = {};     // PV accumulators: thread -> 3 (h,d) pairs x 8 qb
    float z2acc[3][8] = {};   // Z2 partials (wave-h mapping)

    for (int kt = 0; kt < 16; ++kt) {
        // (a) stage prev tile: prev[b, i, q0+qb, kt*64 ..]
        for (int idx = tid; idx < 1536; idx += 256) {
            const int k4 = idx & 15, qb = (idx >> 4) & 7, i = idx >> 7;
            float4 v = *(const float4*)&prev[((size_t)(b * HH + i) * SS + q0 + qb) * SS + kt * 64 + k4 * 4];
            *(float4*)&prevt[i][qb][k4 * 4] = v;
        }
        __syncthreads();

        // (b) recompute scores -> p1 -> mix with conv(prev) -> e2
        #pragma unroll
        for (int hi = 0; hi < 3; ++hi) {
            const int h = hi * 4 + wave;
            float s[8] = {};
            const float* kpp = Kt + (size_t)(b * HH + h) * DHH * SS + kt * 64 + lane;
            #pragma unroll 4
            for (int d = 0; d < 64; d += 4) {
                const float kv0 = kpp[(d + 0) << 10];
                const float kv1 = kpp[(d + 1) << 10];
                const float kv2 = kpp[(d + 2) << 10];
                const float kv3 = kpp[(d + 3) << 10];
                #pragma unroll
                for (int qb = 0; qb < 8; ++qb) {
                    float4 qv = *(const float4*)&Qs[h][qb][d];
                    s[qb] = fmaf(qv.x, kv0, s[qb]);
                    s[qb] = fmaf(qv.y, kv1, s[qb]);
                    s[qb] = fmaf(qv.z, kv2, s[qb]);
                    s[qb] = fmaf(qv.w, kv3, s[qb]);
                }
            }
            const float mk = mask[b * SS + kt * 64 + lane];
            #pragma unroll
            for (int qb = 0; qb < 8; ++qb) {
                const float p1 = __expf(s[qb] * 0.125f + mk) * invZ1[hi][qb];
                float mix = cbs[h];
                #pragma unroll
                for (int i = 0; i < 12; ++i)
                    mix = fmaf(cws[h][i], prevt[i][qb][lane], mix);
                const float e2 = __expf(0.5f * mix + 0.5f * p1);
                e2s[h][qb][lane] = e2;
                z2acc[hi][qb] += e2;
            }
        }
        __syncthreads();

        // (c) PV accumulate: thread p = tid + j*256 -> (h = p/64, d = p%64)
        #pragma unroll
        for (int j = 0; j < 3; ++j) {
            const int p = tid + j * 256;
            const int h = p >> 6, d = p & 63;
            const float* vp = V + ((size_t)(b * HH + h) * SS + kt * 64) * DHH + d;
            #pragma unroll 4
            for (int kl = 0; kl < 64; kl += 4) {
                const float v0 = vp[(kl + 0) * 64];
                const float v1 = vp[(kl + 1) * 64];
                const float v2 = vp[(kl + 2) * 64];
                const float v3 = vp[(kl + 3) * 64];
                #pragma unroll
                for (int qb = 0; qb < 8; ++qb) {
                    float4 e = *(const float4*)&e2s[h][qb][kl];
                    acc[j][qb] = fmaf(e.x, v0, acc[j][qb]);
                    acc[j][qb] = fmaf(e.y, v1, acc[j][qb]);
                    acc[j][qb] = fmaf(e.z, v2, acc[j][qb]);
                    acc[j][qb] = fmaf(e.w, v3, acc[j][qb]);
                }
            }
        }
        __syncthreads();
    }

    // ---- Z2 reduce ----
    #pragma unroll
    for (int hi = 0; hi < 3; ++hi) {
        const int h = hi * 4 + wave;
        #pragma unroll
        for (int qb = 0; qb < 8; ++qb) {
            float z = z2acc[hi][qb];
            for (int off = 32; off; off >>= 1) z += __shfl_xor(z, off);
            if (lane == 0) Z2s[h][qb] = z;
        }
    }
    __syncthreads();

    // ---- normalize + write ctx [B,S,D] ----
    #pragma unroll
    for (int j = 0; j < 3; ++j) {
        const int p = tid + j * 256;
        const int h = p >> 6, d = p & 63;
        #pragma unroll
        for (int qb = 0; qb < 8; ++qb) {
            const float o = acc[j][qb] / Z2s[h][qb];
            ctx[((size_t)(b * SS + q0 + qb) * DD) + h * DHH + d] = o;
        }
    }
}

// ======================================================================
// Residual + LayerNorm, one block per row of [4096, 768]
// ======================================================================
__global__ __launch_bounds__(256)
void ln_kernel(const float* __restrict__ go, const float* __restrict__ hid,
               const float* __restrict__ lw, const float* __restrict__ lb,
               float* __restrict__ out)
{
    const int row = blockIdx.x;
    const int tid = threadIdx.x;
    const int lane = tid & 63, wave = tid >> 6;
    __shared__ float wsum[4], wsq[4];

    float x[3];
    float ssum = 0.f, ssq = 0.f;
    #pragma unroll
    for (int j = 0; j < 3; ++j) {
        const int n = tid + j * 256;
        const float v = go[(size_t)row * DD + n] + hid[(size_t)row * DD + n];
        x[j] = v; ssum += v; ssq += v * v;
    }
    for (int off = 32; off; off >>= 1) {
        ssum += __shfl_xor(ssum, off);
        ssq  += __shfl_xor(ssq, off);
    }
    if (lane == 0) { wsum[wave] = ssum; wsq[wave] = ssq; }
    __syncthreads();
    const float tsum = wsum[0] + wsum[1] + wsum[2] + wsum[3];
    const float tsq  = wsq[0] + wsq[1] + wsq[2] + wsq[3];
    const float mean = tsum * (1.0f / 768.0f);
    const float var  = tsq * (1.0f / 768.0f) - mean * mean;
    const float rstd = rsqrtf(var + 1e-12f);
    #pragma unroll
    for (int j = 0; j < 3; ++j) {
        const int n = tid + j * 256;
        out[(size_t)row * DD + n] = lw[n] * ((x[j] - mean) * rstd) + lb[n];
    }
}

extern "C" void kernel_launch(void* const* d_in, const int* in_sizes, int n_in,
                              void* d_out, int out_size, void* d_ws, size_t ws_size,
                              hipStream_t stream)
{
    const float* hidden = (const float*)d_in[0];
    const float* mask   = (const float*)d_in[1];
    const float* prev   = (const float*)d_in[2];
    const float* Wq = (const float*)d_in[3];  const float* bq = (const float*)d_in[4];
    const float* Wk = (const float*)d_in[5];  const float* bk = (const float*)d_in[6];
    const float* Wv = (const float*)d_in[7];  const float* bv = (const float*)d_in[8];
    const float* cw = (const float*)d_in[9];  const float* cb = (const float*)d_in[10];
    const float* Wo = (const float*)d_in[11]; const float* bo = (const float*)d_in[12];
    const float* lw = (const float*)d_in[13]; const float* lb = (const float*)d_in[14];
    float* out = (float*)d_out;

    float* ws   = (float*)d_ws;
    const size_t BUF = (size_t)BB * SS * DD;   // 3,145,728 floats = 12 MiB
    float* Qb   = ws;
    float* Kt   = ws + BUF;
    float* Vb   = ws + 2 * BUF;
    float* ctx  = ws + 3 * BUF;
    float* gout = ws;              // reuse Q buffer after attention consumes it

    dim3 gg(64, 12), blk(256);
    gemm768_kernel<<<gg, blk, 0, stream>>>(hidden, Wq, bq, Qb, 0);
    gemm768_kernel<<<gg, blk, 0, stream>>>(hidden, Wk, bk, Kt, 1);
    gemm768_kernel<<<gg, blk, 0, stream>>>(hidden, Wv, bv, Vb, 0);
    attn_kernel<<<dim3(512), blk, 0, stream>>>(Qb, Kt, Vb, prev, mask, cw, cb, ctx);
    gemm768_kernel<<<gg, blk, 0, stream>>>(ctx, Wo, bo, gout, 2);
    ln_kernel<<<dim3(4096), blk, 0, stream>>>(gout, hidden, lw, lb, out);
}

// Round 3
// 1170.820 us; speedup vs baseline: 2.1862x; 2.1862x over previous
//
#include <hip/hip_runtime.h>
#include <math.h>

#define BB 4
#define SS 1024
#define DD 768
#define HH 12
#define DHH 64

__device__ __forceinline__ unsigned int f2bf(float f) {
    unsigned int u = __float_as_uint(f);
    return (u + 0x7FFFu + ((u >> 16) & 1u)) >> 16;   // RNE bf16
}
__device__ __forceinline__ float bf2f(unsigned int h) {
    return __uint_as_float(h << 16);
}

// ======================================================================
// GEMM: C = A[M=4096,768] @ W[768,768] + bias
//   mode 0: out[b][h][s][d]  [B,H,S,DH]    mode 2: out[m][n] row-major
// ======================================================================
__global__ __launch_bounds__(256)
void gemm768_kernel(const float* __restrict__ A, const float* __restrict__ W,
                    const float* __restrict__ bias, float* __restrict__ out,
                    int mode)
{
    __shared__ float As[16][68];
    __shared__ float Bs[16][64];
    const int tid = threadIdx.x;
    const int tx = tid & 15, ty = tid >> 4;
    const int m0 = blockIdx.x * 64;
    const int n0 = blockIdx.y * 64;
    const int arow = tid >> 2, akq = tid & 3;

    float c[4][4] = {};

    for (int k0 = 0; k0 < 768; k0 += 16) {
        float4 av = *(const float4*)&A[(m0 + arow) * 768 + k0 + akq * 4];
        float4 bv = *(const float4*)&W[(k0 + ty) * 768 + n0 + tx * 4];
        As[akq * 4 + 0][arow] = av.x;
        As[akq * 4 + 1][arow] = av.y;
        As[akq * 4 + 2][arow] = av.z;
        As[akq * 4 + 3][arow] = av.w;
        *(float4*)&Bs[ty][tx * 4] = bv;
        __syncthreads();
        #pragma unroll
        for (int kk = 0; kk < 16; ++kk) {
            float4 a = *(const float4*)&As[kk][ty * 4];
            float4 b = *(const float4*)&Bs[kk][tx * 4];
            float am[4] = {a.x, a.y, a.z, a.w};
            float bn[4] = {b.x, b.y, b.z, b.w};
            #pragma unroll
            for (int i = 0; i < 4; ++i)
                #pragma unroll
                for (int j = 0; j < 4; ++j)
                    c[i][j] = fmaf(am[i], bn[j], c[i][j]);
        }
        __syncthreads();
    }

    #pragma unroll
    for (int i = 0; i < 4; ++i) {
        const int m = m0 + ty * 4 + i;
        const int b = m >> 10, s = m & 1023;
        #pragma unroll
        for (int j = 0; j < 4; ++j) {
            const int n = n0 + tx * 4 + j;
            const float val = c[i][j] + bias[n];
            if (mode == 0) {
                const int h = n >> 6, d = n & 63;
                out[(((b * HH + h) * SS) + s) * DHH + d] = val;
            } else {
                out[m * DD + n] = val;
            }
        }
    }
}

// ======================================================================
// Kernel A: E1[b,h,q,k] = exp(Q.K/8 + mask) as bf16 ; Z1[b,h,q] = row sum
// block = (b, h, 64 q rows); 256 threads, 4x4 frags; K tiles LDS-staged
// with register double-buffering. 768 blocks.
// ======================================================================
__global__ __launch_bounds__(256)
void qk_exp_kernel(const float* __restrict__ Q, const float* __restrict__ K,
                   const float* __restrict__ mask,
                   unsigned short* __restrict__ E1, float* __restrict__ Z1)
{
    __shared__ float Qs[64][68];      // [d][q]
    __shared__ float Ks[2][64][68];   // [buf][d][k]

    const int tid = threadIdx.x;
    const int tx = tid & 15, ty = tid >> 4;
    const int bid = blockIdx.x;
    const int b  = bid / (HH * 16);
    const int h  = (bid / 16) % HH;
    const int q0 = (bid & 15) * 64;

    const float* Qbase = Q + ((size_t)(b * HH + h) * SS + q0) * DHH;
    const float* Kbase = K + (size_t)(b * HH + h) * SS * DHH;

    // stage Q tile [64q][64d] -> Qs[d][q], and K tile kt=0 -> Ks[0]
    #pragma unroll
    for (int r = 0; r < 4; ++r) {
        const int idx = tid + r * 256;
        const int q = idx >> 4, d4 = (idx & 15) * 4;
        float4 v = *(const float4*)&Qbase[q * DHH + d4];
        Qs[d4 + 0][q] = v.x; Qs[d4 + 1][q] = v.y;
        Qs[d4 + 2][q] = v.z; Qs[d4 + 3][q] = v.w;
        float4 kv = *(const float4*)&Kbase[q * DHH + d4];   // k-row = q idx
        Ks[0][d4 + 0][q] = kv.x; Ks[0][d4 + 1][q] = kv.y;
        Ks[0][d4 + 2][q] = kv.z; Ks[0][d4 + 3][q] = kv.w;
    }
    __syncthreads();

    float z[4] = {};
    int cur = 0;

    for (int kt = 0; kt < 16; ++kt) {
        // prefetch next K tile into registers
        float4 kreg[4];
        if (kt < 15) {
            #pragma unroll
            for (int r = 0; r < 4; ++r) {
                const int idx = tid + r * 256;
                const int kr = idx >> 4, d4 = (idx & 15) * 4;
                kreg[r] = *(const float4*)&Kbase[((kt + 1) * 64 + kr) * DHH + d4];
            }
        }

        float c[4][4] = {};
        #pragma unroll
        for (int d = 0; d < 64; ++d) {
            float4 a = *(const float4*)&Qs[d][ty * 4];
            float4 bb = *(const float4*)&Ks[cur][d][tx * 4];
            float am[4] = {a.x, a.y, a.z, a.w};
            float bn[4] = {bb.x, bb.y, bb.z, bb.w};
            #pragma unroll
            for (int i = 0; i < 4; ++i)
                #pragma unroll
                for (int j = 0; j < 4; ++j)
                    c[i][j] = fmaf(am[i], bn[j], c[i][j]);
        }

        // epilogue: exp + bf16 store + z accumulate
        float4 mk = *(const float4*)&mask[b * SS + kt * 64 + tx * 4];
        const float mka[4] = {mk.x, mk.y, mk.z, mk.w};
        #pragma unroll
        for (int i = 0; i < 4; ++i) {
            float e[4];
            #pragma unroll
            for (int j = 0; j < 4; ++j)
                e[j] = __expf(c[i][j] * 0.125f + mka[j]);
            z[i] += (e[0] + e[1]) + (e[2] + e[3]);
            uint2 pk;
            pk.x = f2bf(e[0]) | (f2bf(e[1]) << 16);
            pk.y = f2bf(e[2]) | (f2bf(e[3]) << 16);
            *(uint2*)&E1[((size_t)(b * HH + h) * SS + q0 + ty * 4 + i) * SS + kt * 64 + tx * 4] = pk;
        }

        if (kt < 15) {
            #pragma unroll
            for (int r = 0; r < 4; ++r) {
                const int idx = tid + r * 256;
                const int kr = idx >> 4, d4 = (idx & 15) * 4;
                Ks[cur ^ 1][d4 + 0][kr] = kreg[r].x;
                Ks[cur ^ 1][d4 + 1][kr] = kreg[r].y;
                Ks[cur ^ 1][d4 + 2][kr] = kreg[r].z;
                Ks[cur ^ 1][d4 + 3][kr] = kreg[r].w;
            }
        }
        __syncthreads();
        cur ^= 1;
    }

    // reduce z over the 16 tx lanes of each q-row group
    #pragma unroll
    for (int i = 0; i < 4; ++i) {
        float zz = z[i];
        zz += __shfl_xor(zz, 1);
        zz += __shfl_xor(zz, 2);
        zz += __shfl_xor(zz, 4);
        zz += __shfl_xor(zz, 8);
        if (tx == 0)
            Z1[(size_t)(b * HH + h) * SS + q0 + ty * 4 + i] = zz;
    }
}

// ======================================================================
// Kernel B: e2 = exp(0.5*conv(prev) + 0.5*E1/Z1); ctx = (e2 @ V) / sum(e2)
// block = (b, 8 q rows) all 12 heads; 512 blocks, 256 threads.
// ======================================================================
__global__ __launch_bounds__(256)
void attn2_kernel(const unsigned short* __restrict__ E1, const float* __restrict__ Z1,
                  const float* __restrict__ V, const float* __restrict__ prev,
                  const float* __restrict__ cw, const float* __restrict__ cb,
                  float* __restrict__ ctx)
{
    __shared__ float prevt[2][12][8][64];   // 48 KiB (double-buffered)
    __shared__ float e2s[12][8][64];        // 24 KiB
    __shared__ float invZ1s[12][8];
    __shared__ float Z2s[12][8];
    __shared__ float cws[12][12];
    __shared__ float cbs[12];

    const int tid  = threadIdx.x;
    const int lane = tid & 63;
    const int wave = tid >> 6;
    const int blk  = blockIdx.x;
    const int b    = blk >> 7;
    const int q0   = (blk & 127) * 8;

    if (tid < 144) cws[tid / 12][tid % 12] = cw[tid];
    if (tid < 12)  cbs[tid] = cb[tid];
    if (tid < 96) {
        const int h = tid >> 3, qb = tid & 7;
        invZ1s[h][qb] = 1.0f / Z1[(size_t)(b * HH + h) * SS + q0 + qb];
    }
    // stage prev tile kt=0
    #pragma unroll
    for (int t = 0; t < 6; ++t) {
        const int idx = tid + t * 256;
        const int k4 = idx & 15, qb = (idx >> 4) & 7, i = idx >> 7;
        *(float4*)&prevt[0][i][qb][k4 * 4] =
            *(const float4*)&prev[((size_t)(b * HH + i) * SS + q0 + qb) * SS + k4 * 4];
    }
    __syncthreads();

    float acc[3][8] = {};
    float z2acc[3][8] = {};
    int cur = 0;

    for (int kt = 0; kt < 16; ++kt) {
        // prefetch next prev tile into registers
        float4 pregs[6];
        if (kt < 15) {
            #pragma unroll
            for (int t = 0; t < 6; ++t) {
                const int idx = tid + t * 256;
                const int k4 = idx & 15, qb = (idx >> 4) & 7, i = idx >> 7;
                pregs[t] = *(const float4*)&prev[((size_t)(b * HH + i) * SS + q0 + qb) * SS + (kt + 1) * 64 + k4 * 4];
            }
        }

        // prefetch E1 for this tile (3 heads x 8 q rows, this lane's k)
        unsigned short e1r[3][8];
        #pragma unroll
        for (int hi = 0; hi < 3; ++hi) {
            const int h = hi * 4 + wave;
            #pragma unroll
            for (int qb = 0; qb < 8; ++qb)
                e1r[hi][qb] = E1[((size_t)(b * HH + h) * SS + q0 + qb) * SS + kt * 64 + lane];
        }

        // e2 phase
        #pragma unroll
        for (int qb = 0; qb < 8; ++qb) {
            float pv[12];
            #pragma unroll
            for (int i = 0; i < 12; ++i) pv[i] = prevt[cur][i][qb][lane];
            #pragma unroll
            for (int hi = 0; hi < 3; ++hi) {
                const int h = hi * 4 + wave;
                float mix = cbs[h];
                #pragma unroll
                for (int i = 0; i < 12; ++i)
                    mix = fmaf(cws[h][i], pv[i], mix);
                const float p1 = bf2f(e1r[hi][qb]) * invZ1s[h][qb];
                const float e2 = __expf(0.5f * mix + 0.5f * p1);
                e2s[h][qb][lane] = e2;
                z2acc[hi][qb] += e2;
            }
        }
        __syncthreads();   // e2s ready; prevt[cur] consumed

        // write next prev tile (other buffer) — overlaps with PV below
        if (kt < 15) {
            #pragma unroll
            for (int t = 0; t < 6; ++t) {
                const int idx = tid + t * 256;
                const int k4 = idx & 15, qb = (idx >> 4) & 7, i = idx >> 7;
                *(float4*)&prevt[cur ^ 1][i][qb][k4 * 4] = pregs[t];
            }
        }

        // PV phase: thread p -> (h, d); 8-deep V-load pipeline
        #pragma unroll
        for (int j = 0; j < 3; ++j) {
            const int p = tid + j * 256;
            const int h = p >> 6, d = p & 63;
            const float* vp = V + ((size_t)(b * HH + h) * SS + kt * 64) * DHH + d;
            #pragma unroll
            for (int kl = 0; kl < 64; kl += 8) {
                float v[8];
                #pragma unroll
                for (int t = 0; t < 8; ++t) v[t] = vp[(kl + t) * DHH];
                #pragma unroll
                for (int qb = 0; qb < 8; ++qb) {
                    float4 elo = *(const float4*)&e2s[h][qb][kl];
                    float4 ehi = *(const float4*)&e2s[h][qb][kl + 4];
                    float a = acc[j][qb];
                    a = fmaf(elo.x, v[0], a); a = fmaf(elo.y, v[1], a);
                    a = fmaf(elo.z, v[2], a); a = fmaf(elo.w, v[3], a);
                    a = fmaf(ehi.x, v[4], a); a = fmaf(ehi.y, v[5], a);
                    a = fmaf(ehi.z, v[6], a); a = fmaf(ehi.w, v[7], a);
                    acc[j][qb] = a;
                }
            }
        }
        __syncthreads();   // e2s consumed; prevt[cur^1] ready
        cur ^= 1;
    }

    // Z2 reduce across the 64 lanes
    #pragma unroll
    for (int hi = 0; hi < 3; ++hi) {
        const int h = hi * 4 + wave;
        #pragma unroll
        for (int qb = 0; qb < 8; ++qb) {
            float zz = z2acc[hi][qb];
            for (int off = 32; off; off >>= 1) zz += __shfl_xor(zz, off);
            if (lane == 0) Z2s[h][qb] = zz;
        }
    }
    __syncthreads();

    #pragma unroll
    for (int j = 0; j < 3; ++j) {
        const int p = tid + j * 256;
        const int h = p >> 6, d = p & 63;
        #pragma unroll
        for (int qb = 0; qb < 8; ++qb) {
            const float o = acc[j][qb] / Z2s[h][qb];
            ctx[((size_t)(b * SS + q0 + qb) * DD) + h * DHH + d] = o;
        }
    }
}

// ======================================================================
// Residual + LayerNorm
// ======================================================================
__global__ __launch_bounds__(256)
void ln_kernel(const float* __restrict__ go, const float* __restrict__ hid,
               const float* __restrict__ lw, const float* __restrict__ lb,
               float* __restrict__ out)
{
    const int row = blockIdx.x;
    const int tid = threadIdx.x;
    const int lane = tid & 63, wave = tid >> 6;
    __shared__ float wsum[4], wsq[4];

    float x[3];
    float ssum = 0.f, ssq = 0.f;
    #pragma unroll
    for (int j = 0; j < 3; ++j) {
        const int n = tid + j * 256;
        const float v = go[(size_t)row * DD + n] + hid[(size_t)row * DD + n];
        x[j] = v; ssum += v; ssq += v * v;
    }
    for (int off = 32; off; off >>= 1) {
        ssum += __shfl_xor(ssum, off);
        ssq  += __shfl_xor(ssq, off);
    }
    if (lane == 0) { wsum[wave] = ssum; wsq[wave] = ssq; }
    __syncthreads();
    const float tsum = wsum[0] + wsum[1] + wsum[2] + wsum[3];
    const float tsq  = wsq[0] + wsq[1] + wsq[2] + wsq[3];
    const float mean = tsum * (1.0f / 768.0f);
    const float var  = tsq * (1.0f / 768.0f) - mean * mean;
    const float rstd = rsqrtf(var + 1e-12f);
    #pragma unroll
    for (int j = 0; j < 3; ++j) {
        const int n = tid + j * 256;
        out[(size_t)row * DD + n] = lw[n] * ((x[j] - mean) * rstd) + lb[n];
    }
}

extern "C" void kernel_launch(void* const* d_in, const int* in_sizes, int n_in,
                              void* d_out, int out_size, void* d_ws, size_t ws_size,
                              hipStream_t stream)
{
    const float* hidden = (const float*)d_in[0];
    const float* mask   = (const float*)d_in[1];
    const float* prev   = (const float*)d_in[2];
    const float* Wq = (const float*)d_in[3];  const float* bq = (const float*)d_in[4];
    const float* Wk = (const float*)d_in[5];  const float* bk = (const float*)d_in[6];
    const float* Wv = (const float*)d_in[7];  const float* bv = (const float*)d_in[8];
    const float* cw = (const float*)d_in[9];  const float* cb = (const float*)d_in[10];
    const float* Wo = (const float*)d_in[11]; const float* bo = (const float*)d_in[12];
    const float* lw = (const float*)d_in[13]; const float* lb = (const float*)d_in[14];
    float* out = (float*)d_out;

    float* ws = (float*)d_ws;
    const size_t BUF = (size_t)BB * SS * DD;     // 3,145,728 floats
    float* Qb  = ws;
    float* Kb  = ws + BUF;
    float* Vb  = ws + 2 * BUF;
    float* ctx = ws + 3 * BUF;
    float* Z1  = ws + 4 * BUF;                   // 49152 floats
    unsigned short* E1 = (unsigned short*)(ws + 4 * BUF + (size_t)BB * HH * SS);  // 96 MiB bf16
    float* gout = Qb;                            // reuse after attention

    dim3 gg(64, 12), blk(256);
    gemm768_kernel<<<gg, blk, 0, stream>>>(hidden, Wq, bq, Qb, 0);
    gemm768_kernel<<<gg, blk, 0, stream>>>(hidden, Wk, bk, Kb, 0);
    gemm768_kernel<<<gg, blk, 0, stream>>>(hidden, Wv, bv, Vb, 0);
    qk_exp_kernel<<<dim3(BB * HH * 16), blk, 0, stream>>>(Qb, Kb, mask, E1, Z1);
    attn2_kernel<<<dim3(512), blk, 0, stream>>>(E1, Z1, Vb, prev, cw, cb, ctx);
    gemm768_kernel<<<gg, blk, 0, stream>>>(ctx, Wo, bo, gout, 2);
    ln_kernel<<<dim3(4096), blk, 0, stream>>>(gout, hidden, lw, lb, out);
}

// Round 4
// 464.753 us; speedup vs baseline: 5.5075x; 2.5192x over previous
//
#include <hip/hip_runtime.h>
#include <math.h>

#define BB 4
#define SS 1024
#define DD 768
#define HH 12
#define DHH 64

typedef __attribute__((ext_vector_type(8))) short bf16x8;   // 8 bf16 = 4 VGPR
typedef __attribute__((ext_vector_type(4))) float f32x4;    // MFMA acc

__device__ __forceinline__ unsigned int f2bf(float f) {
    unsigned int u = __float_as_uint(f);
    return (u + 0x7FFFu + ((u >> 16) & 1u)) >> 16;   // RNE
}
__device__ __forceinline__ float bf2f(unsigned int h) {
    return __uint_as_float(h << 16);
}

// async global->LDS, 16B per lane. dest must be wave-uniform base (+lane*16 by HW).
__device__ __forceinline__ void glds16(const void* g, void* l) {
    __builtin_amdgcn_global_load_lds(
        (const __attribute__((address_space(1))) void*)g,
        (__attribute__((address_space(3))) void*)l, 16, 0, 0);
}

// ======================================================================
// prep: fp32 -> bf16 convert of hidden
// ======================================================================
__global__ __launch_bounds__(256)
void cvt_hidden_kernel(const float* __restrict__ src, unsigned short* __restrict__ dst)
{
    const int idx = (blockIdx.x * 256 + threadIdx.x) * 8;
    float4 a = *(const float4*)&src[idx];
    float4 b = *(const float4*)&src[idx + 4];
    uint4 p;
    p.x = f2bf(a.x) | (f2bf(a.y) << 16);
    p.y = f2bf(a.z) | (f2bf(a.w) << 16);
    p.z = f2bf(b.x) | (f2bf(b.y) << 16);
    p.w = f2bf(b.z) | (f2bf(b.w) << 16);
    *(uint4*)&dst[idx] = p;
}

// ======================================================================
// prep: W[k][n] fp32 -> Wt[w][n][k] bf16 (transposed, n-major)
// ======================================================================
__global__ __launch_bounds__(256)
void transpose_w_kernel(const float* __restrict__ Wq, const float* __restrict__ Wk,
                        const float* __restrict__ Wv, const float* __restrict__ Wo,
                        unsigned short* __restrict__ Wt)
{
    __shared__ float tile[32][33];
    const int t = threadIdx.x;
    const int kt = blockIdx.x, nt = blockIdx.y, w = blockIdx.z;
    const float* src = (w == 0) ? Wq : (w == 1) ? Wk : (w == 2) ? Wv : Wo;
    const int r = t >> 3, c4 = (t & 7) * 4;
    float4 v = *(const float4*)&src[(kt * 32 + r) * DD + nt * 32 + c4];
    tile[r][c4 + 0] = v.x; tile[r][c4 + 1] = v.y;
    tile[r][c4 + 2] = v.z; tile[r][c4 + 3] = v.w;
    __syncthreads();
    uint2 p;
    p.x = f2bf(tile[c4 + 0][r]) | (f2bf(tile[c4 + 1][r]) << 16);
    p.y = f2bf(tile[c4 + 2][r]) | (f2bf(tile[c4 + 3][r]) << 16);
    *(uint2*)&Wt[((size_t)w * DD + nt * 32 + r) * DD + kt * 32 + c4] = p;
}

// ======================================================================
// shared MFMA GEMM core: 64x64 tile, K=768 in 12 chunks of 64.
// A rows / B rows both stride 1536B (bf16 K=768). LDS tiles 64x128B with
// XOR swizzle (kb ^= row&7) applied on the glds SOURCE and on reads.
// 4 waves 2x2; wave tile 32x32 (2x2 frags of 16x16).
// ======================================================================
__device__ __forceinline__ void gemm_core64(
    const char* __restrict__ Ag, const char* __restrict__ Bg,
    char* As, char* Bs, int tid, f32x4 (&acc)[2][2])
{
    const int lane = tid & 63;
    const int wr = (tid >> 7) & 1;
    const int wc = (tid >> 6) & 1;
    const int ldst = (tid & 192) << 4;   // wave * 1024 bytes

    for (int c = 0; c < 12; ++c) {
        const int kbyte = c * 128;
        #pragma unroll
        for (int i = 0; i < 2; ++i) {
            const int s = i * 256 + tid;
            const int row = s >> 3, kb = s & 7;
            const size_t off = (size_t)row * 1536 + kbyte + ((kb ^ (row & 7)) << 4);
            glds16(Ag + off, As + i * 4096 + ldst);
            glds16(Bg + off, Bs + i * 4096 + ldst);
        }
        __syncthreads();
        #pragma unroll
        for (int ks = 0; ks < 2; ++ks) {
            const int kb = ks * 4 + (lane >> 4);
            bf16x8 a[2], b[2];
            #pragma unroll
            for (int mi = 0; mi < 2; ++mi) {
                const int row = wr * 32 + mi * 16 + (lane & 15);
                a[mi] = *(const bf16x8*)(As + row * 128 + ((kb ^ (row & 7)) << 4));
            }
            #pragma unroll
            for (int ni = 0; ni < 2; ++ni) {
                const int row = wc * 32 + ni * 16 + (lane & 15);
                b[ni] = *(const bf16x8*)(Bs + row * 128 + ((kb ^ (row & 7)) << 4));
            }
            #pragma unroll
            for (int mi = 0; mi < 2; ++mi)
                #pragma unroll
                for (int ni = 0; ni < 2; ++ni)
                    acc[mi][ni] = __builtin_amdgcn_mfma_f32_16x16x32_bf16(
                        a[mi], b[ni], acc[mi][ni], 0, 0, 0);
        }
        __syncthreads();
    }
}

// ======================================================================
// QKV projection: grid (64 m-tiles, 36 n-tiles); by/12 selects weight.
// Q,K -> bf16 [B,H,S,DH]; V -> bf16 [B,H,DH,S] (transposed).
// ======================================================================
__global__ __launch_bounds__(256)
void qkv_gemm_kernel(const unsigned short* __restrict__ hbf, const unsigned short* __restrict__ Wt,
                     const float* __restrict__ bq, const float* __restrict__ bk,
                     const float* __restrict__ bv,
                     unsigned short* __restrict__ Qb, unsigned short* __restrict__ Kb,
                     unsigned short* __restrict__ Vtb)
{
    __shared__ __align__(16) char As[8192];
    __shared__ __align__(16) char Bs[8192];
    const int tid = threadIdx.x;
    const int m0 = blockIdx.x * 64;
    const int w = blockIdx.y / 12;
    const int n0w = (blockIdx.y % 12) * 64;

    f32x4 acc[2][2];
    const f32x4 z4 = {0.f, 0.f, 0.f, 0.f};
    acc[0][0] = z4; acc[0][1] = z4; acc[1][0] = z4; acc[1][1] = z4;

    const char* Ag = (const char*)hbf + (size_t)m0 * 1536;
    const char* Bg = (const char*)Wt + ((size_t)w * DD + n0w) * 1536;
    gemm_core64(Ag, Bg, As, Bs, tid, acc);

    const int lane = tid & 63;
    const int wr = (tid >> 7) & 1, wc = (tid >> 6) & 1;
    const float* bias = (w == 0) ? bq : (w == 1) ? bk : bv;
    #pragma unroll
    for (int mi = 0; mi < 2; ++mi) {
        #pragma unroll
        for (int ni = 0; ni < 2; ++ni) {
            const int nw = n0w + wc * 32 + ni * 16 + (lane & 15);
            const int h = nw >> 6, d = nw & 63;
            const float bb = bias[nw];
            const int mrow = m0 + wr * 32 + mi * 16 + (lane >> 4) * 4;
            const int b = mrow >> 10, s = mrow & 1023;
            if (w == 2) {
                uint2 p;
                p.x = f2bf(acc[mi][ni][0] + bb) | (f2bf(acc[mi][ni][1] + bb) << 16);
                p.y = f2bf(acc[mi][ni][2] + bb) | (f2bf(acc[mi][ni][3] + bb) << 16);
                *(uint2*)&Vtb[(((size_t)b * HH + h) * DHH + d) * SS + s] = p;
            } else {
                unsigned short* dst = (w == 0) ? Qb : Kb;
                #pragma unroll
                for (int r = 0; r < 4; ++r)
                    dst[(((size_t)b * HH + h) * SS + (s + r)) * DHH + d] =
                        (unsigned short)f2bf(acc[mi][ni][r] + bb);
            }
        }
    }
}

// ======================================================================
// qk_exp: block = (b,h, 64 q rows); E1 = exp(QK^T/8 + mask) bf16; Z1 row sums.
// K staged per 256-k chunk (32KB LDS, swizzled); Q frags direct from global.
// ======================================================================
__global__ __launch_bounds__(256)
void qk_exp_kernel(const unsigned short* __restrict__ Qb, const unsigned short* __restrict__ Kb,
                   const float* __restrict__ mask,
                   unsigned short* __restrict__ E1, float* __restrict__ Z1)
{
    __shared__ __align__(16) char Ks[32768];
    const int tid = threadIdx.x;
    const int lane = tid & 63;
    const int wv = tid >> 6;
    const int bh = blockIdx.x >> 4;
    const int q0 = (blockIdx.x & 15) * 64;
    const int b = bh / HH;
    const int qw = q0 + wv * 16;
    const int ldst = (tid & 192) << 4;

    // Q A-frags (wave's 16 q rows), direct 16B loads
    const char* Qrow = (const char*)Qb + ((size_t)bh * SS + qw + (lane & 15)) * 128;
    bf16x8 aq0 = *(const bf16x8*)(Qrow + (lane >> 4) * 16);
    bf16x8 aq1 = *(const bf16x8*)(Qrow + 64 + (lane >> 4) * 16);

    float zr[4] = {0.f, 0.f, 0.f, 0.f};
    const char* Kbase = (const char*)Kb + (size_t)bh * SS * 128;

    for (int c = 0; c < 4; ++c) {
        #pragma unroll
        for (int i = 0; i < 8; ++i) {
            const int s = i * 256 + tid;
            const int row = s >> 3, kb = s & 7;
            glds16(Kbase + (size_t)(c * 256 + row) * 128 + ((kb ^ (row & 7)) << 4),
                   Ks + i * 4096 + ldst);
        }
        __syncthreads();
        #pragma unroll
        for (int nf = 0; nf < 16; ++nf) {
            const int krow = nf * 16 + (lane & 15);
            const int kx = krow & 7;
            bf16x8 b0 = *(const bf16x8*)(Ks + krow * 128 + (((lane >> 4) ^ kx) << 4));
            bf16x8 b1 = *(const bf16x8*)(Ks + krow * 128 + (((4 + (lane >> 4)) ^ kx) << 4));
            f32x4 accf = {0.f, 0.f, 0.f, 0.f};
            accf = __builtin_amdgcn_mfma_f32_16x16x32_bf16(aq0, b0, accf, 0, 0, 0);
            accf = __builtin_amdgcn_mfma_f32_16x16x32_bf16(aq1, b1, accf, 0, 0, 0);
            const int kcol = c * 256 + krow;
            const float mk = mask[b * SS + kcol];
            #pragma unroll
            for (int r = 0; r < 4; ++r) {
                const int q = qw + (lane >> 4) * 4 + r;
                const float e = __expf(accf[r] * 0.125f + mk);
                zr[r] += e;
                E1[((size_t)bh * SS + q) * SS + kcol] = (unsigned short)f2bf(e);
            }
        }
        __syncthreads();
    }

    #pragma unroll
    for (int r = 0; r < 4; ++r) {
        float z = zr[r];
        z += __shfl_xor(z, 1); z += __shfl_xor(z, 2);
        z += __shfl_xor(z, 4); z += __shfl_xor(z, 8);
        if ((lane & 15) == 0)
            Z1[(size_t)bh * SS + qw + (lane >> 4) * 4 + r] = z;
    }
}

// ======================================================================
// e2: streaming. block = (b,q). E2 = exp(0.5*conv(prev)+0.5*E1/Z1) written
// IN PLACE over E1 (bf16); Z2 row sums per head.
// ======================================================================
__global__ __launch_bounds__(256)
void e2_kernel(unsigned short* __restrict__ E1, const float* __restrict__ Z1,
               const float* __restrict__ prev, const float* __restrict__ cw,
               const float* __restrict__ cb, float* __restrict__ Z2)
{
    __shared__ float cws[144], cbs[12], izs[12], zred[4][12];
    const int t = threadIdx.x;
    const int b = blockIdx.x >> 10;
    const int q = blockIdx.x & 1023;

    if (t < 144) cws[t] = cw[t];
    if (t < 12) {
        cbs[t] = cb[t];
        izs[t] = 1.0f / Z1[((size_t)(b * HH + t)) * SS + q];
    }
    __syncthreads();

    float z2[12];
    #pragma unroll
    for (int h = 0; h < 12; ++h) z2[h] = 0.f;

    #pragma unroll
    for (int c = 0; c < 2; ++c) {
        const int k = c * 512 + t * 2;
        float2 pv[12];
        #pragma unroll
        for (int i = 0; i < 12; ++i)
            pv[i] = *(const float2*)&prev[(((size_t)(b * HH + i)) * SS + q) * SS + k];
        const size_t e1base = (((size_t)(b * HH)) * SS + q) * SS + k;
        #pragma unroll
        for (int h = 0; h < 12; ++h) {
            float mix0 = cbs[h], mix1 = cbs[h];
            #pragma unroll
            for (int i = 0; i < 12; ++i) {
                mix0 = fmaf(cws[h * 12 + i], pv[i].x, mix0);
                mix1 = fmaf(cws[h * 12 + i], pv[i].y, mix1);
            }
            unsigned int u = *(unsigned int*)&E1[e1base + (size_t)h * SS * SS];
            const float p10 = bf2f(u & 0xFFFFu) * izs[h];
            const float p11 = bf2f(u >> 16) * izs[h];
            const float e0 = __expf(0.5f * (mix0 + p10));
            const float e1 = __expf(0.5f * (mix1 + p11));
            z2[h] += e0 + e1;
            *(unsigned int*)&E1[e1base + (size_t)h * SS * SS] = f2bf(e0) | (f2bf(e1) << 16);
        }
    }

    #pragma unroll
    for (int h = 0; h < 12; ++h) {
        float z = z2[h];
        for (int off = 32; off; off >>= 1) z += __shfl_xor(z, off);
        z2[h] = z;
    }
    if ((t & 63) == 0) {
        const int wv = t >> 6;
        #pragma unroll
        for (int h = 0; h < 12; ++h) zred[wv][h] = z2[h];
    }
    __syncthreads();
    if (t < 12)
        Z2[((size_t)(b * HH + t)) * SS + q] =
            zred[0][t] + zred[1][t] + zred[2][t] + zred[3][t];
}

// ======================================================================
// PV: block = (b,h, 64 q); ctx[q][h*64+d] = (E2 @ V) / Z2, bf16 out.
// E2 tile + Vt tile staged per 64-k chunk (swizzled).
// ======================================================================
__global__ __launch_bounds__(256)
void pv_kernel(const unsigned short* __restrict__ E2, const float* __restrict__ Z2,
               const unsigned short* __restrict__ Vtb, unsigned short* __restrict__ ctx)
{
    __shared__ __align__(16) char Es[8192];
    __shared__ __align__(16) char Vs[8192];
    const int tid = threadIdx.x;
    const int lane = tid & 63;
    const int wv = tid >> 6;
    const int bh = blockIdx.x >> 4;
    const int q0 = (blockIdx.x & 15) * 64;
    const int b = bh / HH, h = bh % HH;
    const int ldst = (tid & 192) << 4;

    f32x4 acc[4];
    const f32x4 z4 = {0.f, 0.f, 0.f, 0.f};
    acc[0] = z4; acc[1] = z4; acc[2] = z4; acc[3] = z4;

    const char* Ebase = (const char*)E2 + ((size_t)bh * SS + q0) * 2048;
    const char* Vbase = (const char*)Vtb + (size_t)bh * DHH * 2048;

    for (int c = 0; c < 16; ++c) {
        const int kbyte = c * 128;
        #pragma unroll
        for (int i = 0; i < 2; ++i) {
            const int s = i * 256 + tid;
            const int row = s >> 3, kb = s & 7;
            const size_t off = (size_t)row * 2048 + kbyte + ((kb ^ (row & 7)) << 4);
            glds16(Ebase + off, Es + i * 4096 + ldst);
            glds16(Vbase + off, Vs + i * 4096 + ldst);
        }
        __syncthreads();
        #pragma unroll
        for (int ks = 0; ks < 2; ++ks) {
            const int kb = ks * 4 + (lane >> 4);
            const int arow = wv * 16 + (lane & 15);
            bf16x8 a = *(const bf16x8*)(Es + arow * 128 + ((kb ^ (arow & 7)) << 4));
            #pragma unroll
            for (int nf = 0; nf < 4; ++nf) {
                const int vrow = nf * 16 + (lane & 15);
                bf16x8 bb = *(const bf16x8*)(Vs + vrow * 128 + ((kb ^ (vrow & 7)) << 4));
                acc[nf] = __builtin_amdgcn_mfma_f32_16x16x32_bf16(a, bb, acc[nf], 0, 0, 0);
            }
        }
        __syncthreads();
    }

    float iz[4];
    #pragma unroll
    for (int r = 0; r < 4; ++r)
        iz[r] = 1.0f / Z2[(size_t)bh * SS + q0 + wv * 16 + (lane >> 4) * 4 + r];

    #pragma unroll
    for (int nf = 0; nf < 4; ++nf) {
        const int d = nf * 16 + (lane & 15);
        #pragma unroll
        for (int r = 0; r < 4; ++r) {
            const int q = q0 + wv * 16 + (lane >> 4) * 4 + r;
            ctx[((size_t)(b * SS + q)) * DD + h * DHH + d] =
                (unsigned short)f2bf(acc[nf][r] * iz[r]);
        }
    }
}

// ======================================================================
// out-projection: ctx bf16 @ Wo_t -> gout fp32 (+bo)
// ======================================================================
__global__ __launch_bounds__(256)
void o_gemm_kernel(const unsigned short* __restrict__ ctx, const unsigned short* __restrict__ WtO,
                   const float* __restrict__ bo, float* __restrict__ gout)
{
    __shared__ __align__(16) char As[8192];
    __shared__ __align__(16) char Bs[8192];
    const int tid = threadIdx.x;
    const int m0 = blockIdx.x * 64;
    const int n0 = blockIdx.y * 64;

    f32x4 acc[2][2];
    const f32x4 z4 = {0.f, 0.f, 0.f, 0.f};
    acc[0][0] = z4; acc[0][1] = z4; acc[1][0] = z4; acc[1][1] = z4;

    gemm_core64((const char*)ctx + (size_t)m0 * 1536,
                (const char*)WtO + (size_t)n0 * 1536, As, Bs, tid, acc);

    const int lane = tid & 63;
    const int wr = (tid >> 7) & 1, wc = (tid >> 6) & 1;
    #pragma unroll
    for (int mi = 0; mi < 2; ++mi) {
        #pragma unroll
        for (int ni = 0; ni < 2; ++ni) {
            const int n = n0 + wc * 32 + ni * 16 + (lane & 15);
            const float bb = bo[n];
            const int mrow = m0 + wr * 32 + mi * 16 + (lane >> 4) * 4;
            #pragma unroll
            for (int r = 0; r < 4; ++r)
                gout[(size_t)(mrow + r) * DD + n] = acc[mi][ni][r] + bb;
        }
    }
}

// ======================================================================
// Residual + LayerNorm (fp32)
// ======================================================================
__global__ __launch_bounds__(256)
void ln_kernel(const float* __restrict__ go, const float* __restrict__ hid,
               const float* __restrict__ lw, const float* __restrict__ lb,
               float* __restrict__ out)
{
    const int row = blockIdx.x;
    const int tid = threadIdx.x;
    const int lane = tid & 63, wave = tid >> 6;
    __shared__ float wsum[4], wsq[4];

    float x[3];
    float ssum = 0.f, ssq = 0.f;
    #pragma unroll
    for (int j = 0; j < 3; ++j) {
        const int n = tid + j * 256;
        const float v = go[(size_t)row * DD + n] + hid[(size_t)row * DD + n];
        x[j] = v; ssum += v; ssq += v * v;
    }
    for (int off = 32; off; off >>= 1) {
        ssum += __shfl_xor(ssum, off);
        ssq  += __shfl_xor(ssq, off);
    }
    if (lane == 0) { wsum[wave] = ssum; wsq[wave] = ssq; }
    __syncthreads();
    const float tsum = wsum[0] + wsum[1] + wsum[2] + wsum[3];
    const float tsq  = wsq[0] + wsq[1] + wsq[2] + wsq[3];
    const float mean = tsum * (1.0f / 768.0f);
    const float var  = tsq * (1.0f / 768.0f) - mean * mean;
    const float rstd = rsqrtf(var + 1e-12f);
    #pragma unroll
    for (int j = 0; j < 3; ++j) {
        const int n = tid + j * 256;
        out[(size_t)row * DD + n] = lw[n] * ((x[j] - mean) * rstd) + lb[n];
    }
}

extern "C" void kernel_launch(void* const* d_in, const int* in_sizes, int n_in,
                              void* d_out, int out_size, void* d_ws, size_t ws_size,
                              hipStream_t stream)
{
    const float* hidden = (const float*)d_in[0];
    const float* mask   = (const float*)d_in[1];
    const float* prev   = (const float*)d_in[2];
    const float* Wq = (const float*)d_in[3];  const float* bq = (const float*)d_in[4];
    const float* Wk = (const float*)d_in[5];  const float* bk = (const float*)d_in[6];
    const float* Wv = (const float*)d_in[7];  const float* bv = (const float*)d_in[8];
    const float* cw = (const float*)d_in[9];  const float* cb = (const float*)d_in[10];
    const float* Wo = (const float*)d_in[11]; const float* bo = (const float*)d_in[12];
    const float* lw = (const float*)d_in[13]; const float* lb = (const float*)d_in[14];
    float* out = (float*)d_out;

    char* w = (char*)d_ws;
    // byte layout (total ~125 MB; round-3 proved >=145 MB available)
    unsigned short* hbf = (unsigned short*)(w);              //  6 MB  [0, 6291456)
    unsigned short* Wt  = (unsigned short*)(w + 6291456);    //  4.5MB
    unsigned short* Qb  = (unsigned short*)(w + 11010048);   //  6 MB
    unsigned short* Kb  = (unsigned short*)(w + 17301504);   //  6 MB
    unsigned short* Vtb = (unsigned short*)(w + 23592960);   //  6 MB
    unsigned short* E1  = (unsigned short*)(w + 29884416);   // 96 MB (becomes E2 in place)
    float* Z1 = (float*)(w + 130547712);                     // 192 KB
    float* Z2 = (float*)(w + 130744320);                     // 192 KB
    unsigned short* ctx = hbf;                               // alias (hbf dead after QKV)
    float* gout = (float*)(w + 11010048);                    // alias Qb+Kb (12 MB)

    dim3 blk(256);
    cvt_hidden_kernel<<<dim3(1536), blk, 0, stream>>>(hidden, hbf);
    transpose_w_kernel<<<dim3(24, 24, 4), blk, 0, stream>>>(Wq, Wk, Wv, Wo, Wt);
    qkv_gemm_kernel<<<dim3(64, 36), blk, 0, stream>>>(hbf, Wt, bq, bk, bv, Qb, Kb, Vtb);
    qk_exp_kernel<<<dim3(768), blk, 0, stream>>>(Qb, Kb, mask, E1, Z1);
    e2_kernel<<<dim3(4096), blk, 0, stream>>>(E1, Z1, prev, cw, cb, Z2);
    pv_kernel<<<dim3(768), blk, 0, stream>>>(E1, Z2, Vtb, ctx);
    o_gemm_kernel<<<dim3(64, 12), blk, 0, stream>>>(ctx, Wt + (size_t)3 * DD * DD, bo, gout);
    ln_kernel<<<dim3(4096), blk, 0, stream>>>(gout, hidden, lw, lb, out);
}